// Round 1
// baseline (908.665 us; speedup 1.0000x reference)
//
#include <hip/hip_runtime.h>

typedef unsigned short u16;
typedef unsigned int u32;
typedef __attribute__((ext_vector_type(8))) short short8;
typedef __attribute__((ext_vector_type(4))) float f32x4;

#define N_IT 80000
#define SLOT 10240000

__device__ __forceinline__ float wred(float v) {
#pragma unroll
    for (int s = 32; s; s >>= 1) v += __shfl_xor(v, s);
    return v;
}
__device__ __forceinline__ float sigf(float x) { return 1.f / (1.f + expf(-x)); }
__device__ __forceinline__ u16 f2bf(float f) {          // RNE f32->bf16
    u32 x = __float_as_uint(f);
    u32 r = x + 0x7fffu + ((x >> 16) & 1u);
    return (u16)(r >> 16);
}
__device__ __forceinline__ f32x4 mfma16(short8 a, short8 b, f32x4 c) {
    return __builtin_amdgcn_mfma_f32_16x16x32_bf16(a, b, c, 0, 0, 0);
}

// ---------- f32 -> bf16 convert ----------
__global__ __launch_bounds__(256) void k_cvt(const float* __restrict__ x,
                                             u16* __restrict__ o, int n) {
    int i = blockIdx.x * 256 + threadIdx.x;
    if (i < n) o[i] = f2bf(x[i]);
}

// ---------- row L2-normalize (wave per row, lane holds dims 2l,2l+1) ----------
__global__ __launch_bounds__(256) void k_norm(const float* __restrict__ x,
                                              float* __restrict__ xn) {
    int wid = (blockIdx.x * blockDim.x + threadIdx.x) >> 6;
    int l = threadIdx.x & 63;
    size_t base = (size_t)wid * 128;
    float2 v = *(const float2*)(x + base + 2 * l);
    float s = wred(v.x * v.x + v.y * v.y);
    float r = 1.f / sqrtf(s + 1e-12f);
    *(float2*)(xn + base + 2 * l) = make_float2(v.x * r, v.y * r);
}

// ---------- one routing_agg hop (wave per item; z kept in registers) ----------
__global__ __launch_bounds__(256) void k_route(const float* __restrict__ xn,
                                               const int* __restrict__ adj,
                                               float* __restrict__ out) {
    int wid = (blockIdx.x * blockDim.x + threadIdx.x) >> 6;
    int l = threadIdx.x & 63;
    size_t base = (size_t)wid * 128;
    float2 xv = *(const float2*)(xn + base + 2 * l);
    float z0[12], z1[12];
#pragma unroll
    for (int m = 0; m < 12; m++) {
        int nb = adj[(size_t)(wid + 1) * 12 + m] - 1;
        float2 zv = *(const float2*)(xn + (size_t)nb * 128 + 2 * l);
        z0[m] = zv.x; z1[m] = zv.y;
    }
    float u0 = xv.x, u1 = xv.y;
#pragma unroll
    for (int it = 0; it < 4; it++) {
        float p[12]; float mx = -1e30f;
#pragma unroll
        for (int m = 0; m < 12; m++) {
            float t = u0 * z0[m] + u1 * z1[m];
#pragma unroll
            for (int s2 = 32; s2; s2 >>= 1) t += __shfl_xor(t, s2);
            p[m] = t; mx = fmaxf(mx, t);
        }
        float sum = 0.f;
#pragma unroll
        for (int m = 0; m < 12; m++) { p[m] = expf(p[m] - mx); sum += p[m]; }
        float inv = 1.f / sum;
        u0 = xv.x; u1 = xv.y;
#pragma unroll
        for (int m = 0; m < 12; m++) {
            float pm = p[m] * inv;
            u0 += pm * z0[m]; u1 += pm * z1[m];
        }
        float nn = wred(u0 * u0 + u1 * u1);
        float rr = 1.f / sqrtf(nn + 1e-12f);
        u0 *= rr; u1 *= rr;
    }
    *(float2*)(out + base + 2 * l) = make_float2(u0, u1);
}

// ---------- item_vectors = LN(emb[1:] + out1 + out2); also bf16 copy ----------
__global__ __launch_bounds__(256) void k_ln1(const float* __restrict__ x,
                                             const float* __restrict__ o1,
                                             const float* __restrict__ o2,
                                             const float* __restrict__ g,
                                             const float* __restrict__ bb,
                                             float* __restrict__ iv,
                                             u32* __restrict__ ivbf) {
    int wid = (blockIdx.x * blockDim.x + threadIdx.x) >> 6;
    int l = threadIdx.x & 63;
    size_t base = (size_t)wid * 128;
    float2 xa = *(const float2*)(x + base + 2 * l);
    float2 xb = *(const float2*)(o1 + base + 2 * l);
    float2 xc = *(const float2*)(o2 + base + 2 * l);
    float v0 = xa.x + xb.x + xc.x;
    float v1 = xa.y + xb.y + xc.y;
    float s = wred(v0 + v1);
    float q = wred(v0 * v0 + v1 * v1);
    float mean = s * (1.f / 128.f);
    float var = q * (1.f / 128.f) - mean * mean;
    float r = 1.f / sqrtf(var + 1e-5f);
    float2 gg = *(const float2*)(g + 2 * l);
    float2 bg = *(const float2*)(bb + 2 * l);
    float y0 = (v0 - mean) * r * gg.x + bg.x;
    float y1 = (v1 - mean) * r * gg.y + bg.y;
    *(float2*)(iv + base + 2 * l) = make_float2(y0, y1);
    ivbf[(size_t)wid * 64 + l] = ((u32)f2bf(y1) << 16) | f2bf(y0);
}

// ---------- h = leaky_relu(iv @ W1^T + b1) via bf16 MFMA ----------
__global__ __launch_bounds__(256) void k_hmf(const u16* __restrict__ ivbf,
                                             const u16* __restrict__ w1bf,
                                             const float* __restrict__ b1,
                                             float* __restrict__ h) {
    int w = threadIdx.x >> 6, l = threadIdx.x & 63;
    int mt = blockIdx.x * 4 + w;
    int row = mt * 16 + (l & 15);
    int ko = (l >> 4) * 8;
    const u16* ap = ivbf + (size_t)row * 128 + ko;
    short8 A[4];
#pragma unroll
    for (int kb = 0; kb < 4; kb++) A[kb] = *(const short8*)(ap + kb * 32);
    int rowb = mt * 16 + (l >> 4) * 4;
    for (int nt = 0; nt < 8; nt++) {
        int col = nt * 16 + (l & 15);
        const u16* wp = w1bf + col * 128 + ko;
        f32x4 acc = {0.f, 0.f, 0.f, 0.f};
#pragma unroll
        for (int kb = 0; kb < 4; kb++)
            acc = mfma16(A[kb], *(const short8*)(wp + kb * 32), acc);
        float bias = b1[col];
#pragma unroll
        for (int q = 0; q < 4; q++) {
            float v = acc[q] + bias;
            h[(size_t)(rowb + q) * 128 + col] = v >= 0.f ? v : 0.01f * v;
        }
    }
}

// ---------- pop logits -> softmax -> @anchors_emb -> LN2 -> pv (bf16) ----------
__global__ __launch_bounds__(1024) void k_pop2(const float* __restrict__ h,
                                               const float* __restrict__ iv,
                                               const float* __restrict__ W2,
                                               const float* __restrict__ b2,
                                               const float* __restrict__ tau,
                                               const int* __restrict__ anchors,
                                               const float* __restrict__ g2,
                                               const float* __restrict__ bb2,
                                               u32* __restrict__ pvbf) {
    __shared__ float W2T[128][20];
    __shared__ __align__(8) float anch[20][128];
    __shared__ __align__(8) float hst[16][128];
    __shared__ float lst[16][20];
    int tid = threadIdx.x;
    for (int e = tid; e < 20 * 128; e += 1024) {
        int k = e >> 7, d = e & 127;
        W2T[d][k] = W2[e];
        anch[k][d] = iv[(size_t)(anchors[k] - 1) * 128 + d];
    }
    __syncthreads();
    int w = tid >> 6, l = tid & 63;
    int item = blockIdx.x * 16 + w;
    const float* hr = h + (size_t)item * 128;
    float2 hv = *(const float2*)(hr + 2 * l);
    *(float2*)&hst[w][2 * l] = hv;
    if (l < 20) {
        float acc = b2[l];
        for (int j = 0; j < 128; j++) acc += hst[w][j] * W2T[j][l];
        lst[w][l] = acc / tau[0];
    }
    float p[20]; float mx = -1e30f;
#pragma unroll
    for (int k = 0; k < 20; k++) { p[k] = lst[w][k]; mx = fmaxf(mx, p[k]); }
    float sum = 0.f;
#pragma unroll
    for (int k = 0; k < 20; k++) { p[k] = expf(p[k] - mx); sum += p[k]; }
    float inv = 1.f / sum;
    float o0 = 0.f, o1 = 0.f;
#pragma unroll
    for (int k = 0; k < 20; k++) {
        float pk = p[k] * inv;
        float2 av = *(const float2*)&anch[k][2 * l];
        o0 += pk * av.x; o1 += pk * av.y;
    }
    float s = wred(o0 + o1), q = wred(o0 * o0 + o1 * o1);
    float mean = s * (1.f / 128.f);
    float var = q * (1.f / 128.f) - mean * mean;
    float rr = 1.f / sqrtf(var + 1e-5f);
    float2 gg = *(const float2*)(g2 + 2 * l);
    float2 bg = *(const float2*)(bb2 + 2 * l);
    float y0 = (o0 - mean) * rr * gg.x + bg.x;
    float y1 = (o1 - mean) * rr * gg.y + bg.y;
    pvbf[(size_t)item * 64 + l] = ((u32)f2bf(y1) << 16) | f2bf(y0);
}

// ---------- gi_all[512*50][384] = gather(iv/pv)[sess] @ W_ih^T + b_ih ----------
__global__ __launch_bounds__(256) void k_gi(const int* __restrict__ sess,
                                            const u16* __restrict__ ivbf,
                                            const u16* __restrict__ pvbf,
                                            const u16* __restrict__ wbf,
                                            const float* __restrict__ bih,
                                            float* __restrict__ gi) {
    int w = threadIdx.x >> 6, l = threadIdx.x & 63;
    int mt = blockIdx.x * 4 + w;
    int r = mt * 16 + (l & 15);
    int s = r / 50, t = r - s * 50;
    int idx = sess[(s & 255) * 50 + t];
    const u16* srcb = (s < 256) ? ivbf : pvbf;
    int ko = (l >> 4) * 8;
    const short8 Z8 = {0, 0, 0, 0, 0, 0, 0, 0};
    short8 A[4];
    if (idx == 0) {
#pragma unroll
        for (int kb = 0; kb < 4; kb++) A[kb] = Z8;
    } else {
        const u16* rp = srcb + (size_t)(idx - 1) * 128 + ko;
#pragma unroll
        for (int kb = 0; kb < 4; kb++) A[kb] = *(const short8*)(rp + kb * 32);
    }
    int rowb = mt * 16 + (l >> 4) * 4;
    for (int nt = 0; nt < 24; nt++) {
        int gcol = nt * 16 + (l & 15);
        const u16* wp = wbf + gcol * 128 + ko;
        f32x4 acc = {0.f, 0.f, 0.f, 0.f};
#pragma unroll
        for (int kb = 0; kb < 4; kb++)
            acc = mfma16(A[kb], *(const short8*)(wp + kb * 32), acc);
        float bias = bih[gcol];
#pragma unroll
        for (int q = 0; q < 4; q++)
            gi[(size_t)(rowb + q) * 384 + gcol] = acc[q] + bias;
    }
}

// ---------- dual GRU: block b runs seq b (item) and b+256 (pop); W_hh rows in VGPRs ----------
__global__ __launch_bounds__(384, 2) void k_gru(const float* __restrict__ gi,
                                                const float* __restrict__ whh,
                                                const float* __restrict__ bhh,
                                                const int* __restrict__ lengths,
                                                const float* __restrict__ g3,
                                                const float* __restrict__ b3,
                                                const float* __restrict__ g4,
                                                const float* __restrict__ b4,
                                                u32* __restrict__ htbf) {
    __shared__ __align__(16) float hA[2][128], hB[2][128];
    __shared__ float rA[128], zA[128], hnA[128], inA[128];
    __shared__ float rB[128], zB[128], hnB[128], inB[128];
    int g = threadIdx.x, b = blockIdx.x;
    float4 wv[32];
    const float4* wr = (const float4*)(whh + g * 128);
#pragma unroll
    for (int k = 0; k < 32; k++) wv[k] = wr[k];
    float bh = bhh[g];
    if (g < 128) { hA[0][g] = 0.f; hB[0][g] = 0.f; }
    int len = lengths[b];
    const float* giA = gi + (size_t)b * 50 * 384 + g;
    const float* giB = gi + (size_t)(b + 256) * 50 * 384 + g;
    __syncthreads();
    int par = 0;
    for (int t = 0; t < len; t++) {
        float ga = giA[t * 384], gb = giB[t * 384];
        float aA = bh, aB = bh;
#pragma unroll
        for (int k = 0; k < 32; k++) {
            float4 w4 = wv[k];
            float4 ha = *(const float4*)&hA[par][k * 4];
            float4 hb = *(const float4*)&hB[par][k * 4];
            aA += w4.x * ha.x + w4.y * ha.y + w4.z * ha.z + w4.w * ha.w;
            aB += w4.x * hb.x + w4.y * hb.y + w4.z * hb.z + w4.w * hb.w;
        }
        if (g < 128) {
            rA[g] = sigf(ga + aA); rB[g] = sigf(gb + aB);
        } else if (g < 256) {
            zA[g - 128] = sigf(ga + aA); zB[g - 128] = sigf(gb + aB);
        } else {
            inA[g - 256] = ga; hnA[g - 256] = aA;
            inB[g - 256] = gb; hnB[g - 256] = aB;
        }
        __syncthreads();
        if (g < 128) {
            float n = tanhf(inA[g] + rA[g] * hnA[g]);
            hA[par ^ 1][g] = (1.f - zA[g]) * n + zA[g] * hA[par][g];
        } else if (g < 256) {
            int d = g - 128;
            float n = tanhf(inB[d] + rB[d] * hnB[d]);
            hB[par ^ 1][d] = (1.f - zB[d]) * n + zB[d] * hB[par][d];
        }
        __syncthreads();
        par ^= 1;
    }
    int w = g >> 6, l = g & 63;
    if (w == 0) {
        float2 v = *(const float2*)&hA[par][2 * l];
        float s = wred(v.x + v.y), q = wred(v.x * v.x + v.y * v.y);
        float mean = s * (1.f / 128.f), var = q * (1.f / 128.f) - mean * mean;
        float r = 1.f / sqrtf(var + 1e-5f);
        float2 gg = *(const float2*)(g3 + 2 * l), bg = *(const float2*)(b3 + 2 * l);
        float y0 = (v.x - mean) * r * gg.x + bg.x;
        float y1 = (v.y - mean) * r * gg.y + bg.y;
        htbf[(size_t)b * 64 + l] = ((u32)f2bf(y1) << 16) | f2bf(y0);
    } else if (w == 1) {
        float2 v = *(const float2*)&hB[par][2 * l];
        float s = wred(v.x + v.y), q = wred(v.x * v.x + v.y * v.y);
        float mean = s * (1.f / 128.f), var = q * (1.f / 128.f) - mean * mean;
        float r = 1.f / sqrtf(var + 1e-5f);
        float2 gg = *(const float2*)(g4 + 2 * l), bg = *(const float2*)(b4 + 2 * l);
        float y0 = (v.x - mean) * r * gg.x + bg.x;
        float y1 = (v.y - mean) * r * gg.y + bg.y;
        htbf[(size_t)(b + 256) * 64 + l] = ((u32)f2bf(y1) << 16) | f2bf(y0);
    }
}

// ---------- scores: BM=256(all) x BN=64/block, bf16 MFMA, 3 outputs ----------
__global__ __launch_bounds__(256) void k_scores(const u16* __restrict__ htbf,
                                                const u16* __restrict__ ivbf,
                                                const u16* __restrict__ pvbf,
                                                const float* __restrict__ a1,
                                                const float* __restrict__ a2,
                                                float* __restrict__ out) {
    int w = threadIdx.x >> 6, l = threadIdx.x & 63;
    int n0 = blockIdx.x * 64;
    int ko = (l >> 4) * 8;
    short8 Ai[4][4], Ap[4][4];
#pragma unroll
    for (int mi = 0; mi < 4; mi++) {
        int row = w * 64 + mi * 16 + (l & 15);
        const u16* pi = htbf + row * 128 + ko;
        const u16* pp = htbf + (row + 256) * 128 + ko;
#pragma unroll
        for (int kb = 0; kb < 4; kb++) {
            Ai[mi][kb] = *(const short8*)(pi + kb * 32);
            Ap[mi][kb] = *(const short8*)(pp + kb * 32);
        }
    }
    float s1 = sigf(a1[0]), s2 = sigf(a2[0]);
    float* sc = out;
    float* si = out + (size_t)20480000;
    float* sp = out + (size_t)40960000;
    for (int nt = 0; nt < 4; nt++) {
        int col = n0 + nt * 16 + (l & 15);
        const u16* bi = ivbf + (size_t)col * 128 + ko;
        const u16* bp = pvbf + (size_t)col * 128 + ko;
        short8 Bi[4], Bp[4];
#pragma unroll
        for (int kb = 0; kb < 4; kb++) {
            Bi[kb] = *(const short8*)(bi + kb * 32);
            Bp[kb] = *(const short8*)(bp + kb * 32);
        }
#pragma unroll
        for (int mi = 0; mi < 4; mi++) {
            f32x4 ai = {0.f, 0.f, 0.f, 0.f}, ap = {0.f, 0.f, 0.f, 0.f};
#pragma unroll
            for (int kb = 0; kb < 4; kb++) {
                ai = mfma16(Ai[mi][kb], Bi[kb], ai);
                ap = mfma16(Ap[mi][kb], Bp[kb], ap);
            }
            int rowb = w * 64 + mi * 16 + (l >> 4) * 4;
#pragma unroll
            for (int q = 0; q < 4; q++) {
                size_t o = (size_t)(rowb + q) * 80000 + col;
                float vi = ai[q], vp = ap[q];
                si[o] = vi;
                sp[o] = vp;
                sc[o] = s1 * vi + s2 * vp;
            }
        }
    }
}

extern "C" void kernel_launch(void* const* d_in, const int* in_sizes, int n_in,
                              void* d_out, int out_size, void* d_ws, size_t ws_size,
                              hipStream_t stream) {
    (void)in_sizes; (void)n_in; (void)out_size; (void)ws_size;
    const int*   sess    = (const int*)d_in[0];
    const int*   lengths = (const int*)d_in[1];
    const float* tau     = (const float*)d_in[4];
    const int*   adj     = (const int*)d_in[5];
    const int*   anchors = (const int*)d_in[6];
    const float* emb     = (const float*)d_in[7];
    const float* W_ih    = (const float*)d_in[8];
    const float* W_hh    = (const float*)d_in[9];
    const float* b_ih    = (const float*)d_in[10];
    const float* b_hh    = (const float*)d_in[11];
    const float* W1      = (const float*)d_in[12];
    const float* b1      = (const float*)d_in[13];
    const float* W2      = (const float*)d_in[14];
    const float* b2      = (const float*)d_in[15];
    const float* a1      = (const float*)d_in[16];
    const float* a2      = (const float*)d_in[17];
    const float* ln1g = (const float*)d_in[18];
    const float* ln1b = (const float*)d_in[19];
    const float* ln2g = (const float*)d_in[20];
    const float* ln2b = (const float*)d_in[21];
    const float* ln3g = (const float*)d_in[22];
    const float* ln3b = (const float*)d_in[23];
    const float* ln4g = (const float*)d_in[24];
    const float* ln4b = (const float*)d_in[25];

    float* out = (float*)d_out;
    // d_out doubles as scratch; all scratch dead before k_scores overwrites it.
    float* o_iv  = out;              // xn1, later item_vectors (f32)
    float* o_o1  = out + SLOT;       // hop-1 output
    float* o_o2  = out + 2 * SLOT;   // hop-2 output
    float* o_hgi = out + 3 * SLOT;   // h (MLP), later gi_all

    u16* ws16  = (u16*)d_ws;         // needs ~41.3 MB
    u16* ivbf  = ws16;               // 10.24M
    u16* pvbf  = ws16 + 10240000;    // 10.24M
    u16* wihbf = ws16 + 20480000;    // 49152
    u16* htbf  = ws16 + 20529152;    // 65536
    u16* w1bf  = ws16 + 20594688;    // 16384

    k_cvt<<<192, 256, 0, stream>>>(W_ih, wihbf, 49152);
    k_cvt<<<64, 256, 0, stream>>>(W1, w1bf, 16384);
    k_norm<<<20000, 256, 0, stream>>>(emb + 128, o_iv);
    k_route<<<20000, 256, 0, stream>>>(o_iv, adj, o_o1);
    // hop-2 input is already unit-norm (routing ends with normalize) -> reuse directly
    k_route<<<20000, 256, 0, stream>>>(o_o1, adj, o_o2);
    k_ln1<<<20000, 256, 0, stream>>>(emb + 128, o_o1, o_o2, ln1g, ln1b, o_iv, (u32*)ivbf);
    k_hmf<<<1250, 256, 0, stream>>>(ivbf, w1bf, b1, o_hgi);
    k_pop2<<<5000, 1024, 0, stream>>>(o_hgi, o_iv, W2, b2, tau, anchors, ln2g, ln2b, (u32*)pvbf);
    k_gi<<<400, 256, 0, stream>>>(sess, ivbf, pvbf, wihbf, b_ih, o_hgi);
    k_gru<<<256, 384, 0, stream>>>(o_hgi, W_hh, b_hh, lengths, ln3g, ln3b, ln4g, ln4b, (u32*)htbf);
    k_scores<<<1250, 256, 0, stream>>>(htbf, ivbf, pvbf, a1, a2, out);
}

// Round 2
// 796.109 us; speedup vs baseline: 1.1414x; 1.1414x over previous
//
#include <hip/hip_runtime.h>

typedef unsigned short u16;
typedef unsigned int u32;
typedef __attribute__((ext_vector_type(8))) short short8;
typedef __attribute__((ext_vector_type(4))) float f32x4;

#define N_IT 80000
#define SLOT 10240000

__device__ __forceinline__ float wred(float v) {
#pragma unroll
    for (int s = 32; s; s >>= 1) v += __shfl_xor(v, s);
    return v;
}
__device__ __forceinline__ float sigf(float x) { return 1.f / (1.f + expf(-x)); }
__device__ __forceinline__ u16 f2bf(float f) {          // RNE f32->bf16
    u32 x = __float_as_uint(f);
    u32 r = x + 0x7fffu + ((x >> 16) & 1u);
    return (u16)(r >> 16);
}
__device__ __forceinline__ f32x4 mfma16(short8 a, short8 b, f32x4 c) {
    return __builtin_amdgcn_mfma_f32_16x16x32_bf16(a, b, c, 0, 0, 0);
}
// xor-swizzle within 32-lane half (BitMode): pattern = (xor<<10)|0x1F
#define SWZ(v, pat) __int_as_float(__builtin_amdgcn_ds_swizzle(__float_as_int(v), pat))
__device__ __forceinline__ float red16(float t) {   // sum over 16-lane group
    t += SWZ(t, 0x041F);
    t += SWZ(t, 0x081F);
    t += SWZ(t, 0x101F);
    t += SWZ(t, 0x201F);
    return t;
}
__device__ __forceinline__ float dot4(float4 a, float4 b) {
    return a.x * b.x + a.y * b.y + a.z * b.z + a.w * b.w;
}

// ---------- f32 -> bf16 convert ----------
__global__ __launch_bounds__(256) void k_cvt(const float* __restrict__ x,
                                             u16* __restrict__ o, int n) {
    int i = blockIdx.x * 256 + threadIdx.x;
    if (i < n) o[i] = f2bf(x[i]);
}

// ---------- row L2-normalize (wave per row, lane holds dims 2l,2l+1) ----------
__global__ __launch_bounds__(256) void k_norm(const float* __restrict__ x,
                                              float* __restrict__ xn) {
    int wid = (blockIdx.x * blockDim.x + threadIdx.x) >> 6;
    int l = threadIdx.x & 63;
    size_t base = (size_t)wid * 128;
    float2 v = *(const float2*)(x + base + 2 * l);
    float s = wred(v.x * v.x + v.y * v.y);
    float r = 1.f / sqrtf(s + 1e-12f);
    *(float2*)(xn + base + 2 * l) = make_float2(v.x * r, v.y * r);
}

// ---------- one routing_agg hop: 16 lanes/item, 8 dims/lane, 4 items/wave ----------
__global__ __launch_bounds__(256, 3) void k_route(const float* __restrict__ xn,
                                                  const int* __restrict__ adj,
                                                  float* __restrict__ out) {
    int tid = blockIdx.x * 256 + threadIdx.x;
    int item = tid >> 4;
    int sl = threadIdx.x & 15;
    const float4* xr = (const float4*)(xn + (size_t)item * 128 + sl * 8);
    float4 x0 = xr[0], x1 = xr[1];
    // adjacency row: 48 B, same address across the 16-lane group (L1 broadcast)
    const int4* ar = (const int4*)(adj + (size_t)(item + 1) * 12);
    int4 a0 = ar[0], a1 = ar[1], a2 = ar[2];
    int nb[12] = {a0.x, a0.y, a0.z, a0.w, a1.x, a1.y, a1.z, a1.w,
                  a2.x, a2.y, a2.z, a2.w};
    float4 z0[12], z1[12];
#pragma unroll
    for (int m = 0; m < 12; m++) {
        const float4* zr = (const float4*)(xn + (size_t)(nb[m] - 1) * 128 + sl * 8);
        z0[m] = zr[0]; z1[m] = zr[1];
    }
    float4 u0 = x0, u1 = x1;
#pragma unroll
    for (int it = 0; it < 4; it++) {
        float p[12]; float sum = 0.f;
#pragma unroll
        for (int m = 0; m < 12; m++) {
            float t = dot4(u0, z0[m]) + dot4(u1, z1[m]);
            t = red16(t);
            // u,z unit vectors -> |t|<=1: softmax max-subtraction unnecessary
            p[m] = __expf(t);
            sum += p[m];
        }
        float inv = 1.f / sum;
        u0 = x0; u1 = x1;
#pragma unroll
        for (int m = 0; m < 12; m++) {
            float pm = p[m] * inv;
            u0.x += pm * z0[m].x; u0.y += pm * z0[m].y;
            u0.z += pm * z0[m].z; u0.w += pm * z0[m].w;
            u1.x += pm * z1[m].x; u1.y += pm * z1[m].y;
            u1.z += pm * z1[m].z; u1.w += pm * z1[m].w;
        }
        float nn = red16(dot4(u0, u0) + dot4(u1, u1));
        float rr = 1.f / sqrtf(nn + 1e-12f);
        u0.x *= rr; u0.y *= rr; u0.z *= rr; u0.w *= rr;
        u1.x *= rr; u1.y *= rr; u1.z *= rr; u1.w *= rr;
    }
    float4* orow = (float4*)(out + (size_t)item * 128 + sl * 8);
    orow[0] = u0; orow[1] = u1;
}

// ---------- item_vectors = LN(emb[1:] + out1 + out2); also bf16 copy ----------
__global__ __launch_bounds__(256) void k_ln1(const float* __restrict__ x,
                                             const float* __restrict__ o1,
                                             const float* __restrict__ o2,
                                             const float* __restrict__ g,
                                             const float* __restrict__ bb,
                                             float* __restrict__ iv,
                                             u32* __restrict__ ivbf) {
    int wid = (blockIdx.x * blockDim.x + threadIdx.x) >> 6;
    int l = threadIdx.x & 63;
    size_t base = (size_t)wid * 128;
    float2 xa = *(const float2*)(x + base + 2 * l);
    float2 xb = *(const float2*)(o1 + base + 2 * l);
    float2 xc = *(const float2*)(o2 + base + 2 * l);
    float v0 = xa.x + xb.x + xc.x;
    float v1 = xa.y + xb.y + xc.y;
    float s = wred(v0 + v1);
    float q = wred(v0 * v0 + v1 * v1);
    float mean = s * (1.f / 128.f);
    float var = q * (1.f / 128.f) - mean * mean;
    float r = 1.f / sqrtf(var + 1e-5f);
    float2 gg = *(const float2*)(g + 2 * l);
    float2 bg = *(const float2*)(bb + 2 * l);
    float y0 = (v0 - mean) * r * gg.x + bg.x;
    float y1 = (v1 - mean) * r * gg.y + bg.y;
    *(float2*)(iv + base + 2 * l) = make_float2(y0, y1);
    ivbf[(size_t)wid * 64 + l] = ((u32)f2bf(y1) << 16) | f2bf(y0);
}

// ---------- h = leaky_relu(iv @ W1^T + b1) via bf16 MFMA ----------
__global__ __launch_bounds__(256) void k_hmf(const u16* __restrict__ ivbf,
                                             const u16* __restrict__ w1bf,
                                             const float* __restrict__ b1,
                                             float* __restrict__ h) {
    int w = threadIdx.x >> 6, l = threadIdx.x & 63;
    int mt = blockIdx.x * 4 + w;
    int row = mt * 16 + (l & 15);
    int ko = (l >> 4) * 8;
    const u16* ap = ivbf + (size_t)row * 128 + ko;
    short8 A[4];
#pragma unroll
    for (int kb = 0; kb < 4; kb++) A[kb] = *(const short8*)(ap + kb * 32);
    int rowb = mt * 16 + (l >> 4) * 4;
    for (int nt = 0; nt < 8; nt++) {
        int col = nt * 16 + (l & 15);
        const u16* wp = w1bf + col * 128 + ko;
        f32x4 acc = {0.f, 0.f, 0.f, 0.f};
#pragma unroll
        for (int kb = 0; kb < 4; kb++)
            acc = mfma16(A[kb], *(const short8*)(wp + kb * 32), acc);
        float bias = b1[col];
#pragma unroll
        for (int q = 0; q < 4; q++) {
            float v = acc[q] + bias;
            h[(size_t)(rowb + q) * 128 + col] = v >= 0.f ? v : 0.01f * v;
        }
    }
}

// ---------- pop logits -> softmax -> @anchors_emb -> LN2 -> pv (bf16) ----------
__global__ __launch_bounds__(1024) void k_pop2(const float* __restrict__ h,
                                               const float* __restrict__ iv,
                                               const float* __restrict__ W2,
                                               const float* __restrict__ b2,
                                               const float* __restrict__ tau,
                                               const int* __restrict__ anchors,
                                               const float* __restrict__ g2,
                                               const float* __restrict__ bb2,
                                               u32* __restrict__ pvbf) {
    __shared__ float W2T[128][20];
    __shared__ __align__(8) float anch[20][128];
    __shared__ __align__(8) float hst[16][128];
    __shared__ float lst[16][20];
    int tid = threadIdx.x;
    for (int e = tid; e < 20 * 128; e += 1024) {
        int k = e >> 7, d = e & 127;
        W2T[d][k] = W2[e];
        anch[k][d] = iv[(size_t)(anchors[k] - 1) * 128 + d];
    }
    __syncthreads();
    int w = tid >> 6, l = tid & 63;
    int item = blockIdx.x * 16 + w;
    const float* hr = h + (size_t)item * 128;
    float2 hv = *(const float2*)(hr + 2 * l);
    *(float2*)&hst[w][2 * l] = hv;
    if (l < 20) {
        float acc = b2[l];
        for (int j = 0; j < 128; j++) acc += hst[w][j] * W2T[j][l];
        lst[w][l] = acc / tau[0];
    }
    float p[20]; float mx = -1e30f;
#pragma unroll
    for (int k = 0; k < 20; k++) { p[k] = lst[w][k]; mx = fmaxf(mx, p[k]); }
    float sum = 0.f;
#pragma unroll
    for (int k = 0; k < 20; k++) { p[k] = expf(p[k] - mx); sum += p[k]; }
    float inv = 1.f / sum;
    float o0 = 0.f, o1 = 0.f;
#pragma unroll
    for (int k = 0; k < 20; k++) {
        float pk = p[k] * inv;
        float2 av = *(const float2*)&anch[k][2 * l];
        o0 += pk * av.x; o1 += pk * av.y;
    }
    float s = wred(o0 + o1), q = wred(o0 * o0 + o1 * o1);
    float mean = s * (1.f / 128.f);
    float var = q * (1.f / 128.f) - mean * mean;
    float rr = 1.f / sqrtf(var + 1e-5f);
    float2 gg = *(const float2*)(g2 + 2 * l);
    float2 bg = *(const float2*)(bb2 + 2 * l);
    float y0 = (o0 - mean) * rr * gg.x + bg.x;
    float y1 = (o1 - mean) * rr * gg.y + bg.y;
    pvbf[(size_t)item * 64 + l] = ((u32)f2bf(y1) << 16) | f2bf(y0);
}

// ---------- gi_all[512*50][384] = gather(iv/pv)[sess] @ W_ih^T + b_ih ----------
__global__ __launch_bounds__(256) void k_gi(const int* __restrict__ sess,
                                            const u16* __restrict__ ivbf,
                                            const u16* __restrict__ pvbf,
                                            const u16* __restrict__ wbf,
                                            const float* __restrict__ bih,
                                            float* __restrict__ gi) {
    int w = threadIdx.x >> 6, l = threadIdx.x & 63;
    int mt = blockIdx.x * 4 + w;
    int r = mt * 16 + (l & 15);
    int s = r / 50, t = r - s * 50;
    int idx = sess[(s & 255) * 50 + t];
    const u16* srcb = (s < 256) ? ivbf : pvbf;
    int ko = (l >> 4) * 8;
    const short8 Z8 = {0, 0, 0, 0, 0, 0, 0, 0};
    short8 A[4];
    if (idx == 0) {
#pragma unroll
        for (int kb = 0; kb < 4; kb++) A[kb] = Z8;
    } else {
        const u16* rp = srcb + (size_t)(idx - 1) * 128 + ko;
#pragma unroll
        for (int kb = 0; kb < 4; kb++) A[kb] = *(const short8*)(rp + kb * 32);
    }
    int rowb = mt * 16 + (l >> 4) * 4;
    for (int nt = 0; nt < 24; nt++) {
        int gcol = nt * 16 + (l & 15);
        const u16* wp = wbf + gcol * 128 + ko;
        f32x4 acc = {0.f, 0.f, 0.f, 0.f};
#pragma unroll
        for (int kb = 0; kb < 4; kb++)
            acc = mfma16(A[kb], *(const short8*)(wp + kb * 32), acc);
        float bias = bih[gcol];
#pragma unroll
        for (int q = 0; q < 4; q++)
            gi[(size_t)(rowb + q) * 384 + gcol] = acc[q] + bias;
    }
}

// ---------- dual GRU: block b runs seq b (item) and b+256 (pop); W_hh rows in VGPRs ----------
__global__ __launch_bounds__(384, 2) void k_gru(const float* __restrict__ gi,
                                                const float* __restrict__ whh,
                                                const float* __restrict__ bhh,
                                                const int* __restrict__ lengths,
                                                const float* __restrict__ g3,
                                                const float* __restrict__ b3,
                                                const float* __restrict__ g4,
                                                const float* __restrict__ b4,
                                                u32* __restrict__ htbf) {
    __shared__ __align__(16) float hA[2][128], hB[2][128];
    __shared__ float rA[128], zA[128], hnA[128], inA[128];
    __shared__ float rB[128], zB[128], hnB[128], inB[128];
    int g = threadIdx.x, b = blockIdx.x;
    float4 wv[32];
    const float4* wr = (const float4*)(whh + g * 128);
#pragma unroll
    for (int k = 0; k < 32; k++) wv[k] = wr[k];
    float bh = bhh[g];
    if (g < 128) { hA[0][g] = 0.f; hB[0][g] = 0.f; }
    int len = lengths[b];
    const float* giA = gi + (size_t)b * 50 * 384 + g;
    const float* giB = gi + (size_t)(b + 256) * 50 * 384 + g;
    __syncthreads();
    int par = 0;
    for (int t = 0; t < len; t++) {
        float ga = giA[t * 384], gb = giB[t * 384];
        float aA = bh, aB = bh;
#pragma unroll
        for (int k = 0; k < 32; k++) {
            float4 w4 = wv[k];
            float4 ha = *(const float4*)&hA[par][k * 4];
            float4 hb = *(const float4*)&hB[par][k * 4];
            aA += w4.x * ha.x + w4.y * ha.y + w4.z * ha.z + w4.w * ha.w;
            aB += w4.x * hb.x + w4.y * hb.y + w4.z * hb.z + w4.w * hb.w;
        }
        if (g < 128) {
            rA[g] = sigf(ga + aA); rB[g] = sigf(gb + aB);
        } else if (g < 256) {
            zA[g - 128] = sigf(ga + aA); zB[g - 128] = sigf(gb + aB);
        } else {
            inA[g - 256] = ga; hnA[g - 256] = aA;
            inB[g - 256] = gb; hnB[g - 256] = aB;
        }
        __syncthreads();
        if (g < 128) {
            float n = tanhf(inA[g] + rA[g] * hnA[g]);
            hA[par ^ 1][g] = (1.f - zA[g]) * n + zA[g] * hA[par][g];
        } else if (g < 256) {
            int d = g - 128;
            float n = tanhf(inB[d] + rB[d] * hnB[d]);
            hB[par ^ 1][d] = (1.f - zB[d]) * n + zB[d] * hB[par][d];
        }
        __syncthreads();
        par ^= 1;
    }
    int w = g >> 6, l = g & 63;
    if (w == 0) {
        float2 v = *(const float2*)&hA[par][2 * l];
        float s = wred(v.x + v.y), q = wred(v.x * v.x + v.y * v.y);
        float mean = s * (1.f / 128.f), var = q * (1.f / 128.f) - mean * mean;
        float r = 1.f / sqrtf(var + 1e-5f);
        float2 gg = *(const float2*)(g3 + 2 * l), bg = *(const float2*)(b3 + 2 * l);
        float y0 = (v.x - mean) * r * gg.x + bg.x;
        float y1 = (v.y - mean) * r * gg.y + bg.y;
        htbf[(size_t)b * 64 + l] = ((u32)f2bf(y1) << 16) | f2bf(y0);
    } else if (w == 1) {
        float2 v = *(const float2*)&hB[par][2 * l];
        float s = wred(v.x + v.y), q = wred(v.x * v.x + v.y * v.y);
        float mean = s * (1.f / 128.f), var = q * (1.f / 128.f) - mean * mean;
        float r = 1.f / sqrtf(var + 1e-5f);
        float2 gg = *(const float2*)(g4 + 2 * l), bg = *(const float2*)(b4 + 2 * l);
        float y0 = (v.x - mean) * r * gg.x + bg.x;
        float y1 = (v.y - mean) * r * gg.y + bg.y;
        htbf[(size_t)(b + 256) * 64 + l] = ((u32)f2bf(y1) << 16) | f2bf(y0);
    }
}

// ---------- scores: BM=256(all) x BN=64/block, bf16 MFMA, 3 outputs ----------
__global__ __launch_bounds__(256) void k_scores(const u16* __restrict__ htbf,
                                                const u16* __restrict__ ivbf,
                                                const u16* __restrict__ pvbf,
                                                const float* __restrict__ a1,
                                                const float* __restrict__ a2,
                                                float* __restrict__ out) {
    int w = threadIdx.x >> 6, l = threadIdx.x & 63;
    int n0 = blockIdx.x * 64;
    int ko = (l >> 4) * 8;
    short8 Ai[4][4], Ap[4][4];
#pragma unroll
    for (int mi = 0; mi < 4; mi++) {
        int row = w * 64 + mi * 16 + (l & 15);
        const u16* pi = htbf + row * 128 + ko;
        const u16* pp = htbf + (row + 256) * 128 + ko;
#pragma unroll
        for (int kb = 0; kb < 4; kb++) {
            Ai[mi][kb] = *(const short8*)(pi + kb * 32);
            Ap[mi][kb] = *(const short8*)(pp + kb * 32);
        }
    }
    float s1 = sigf(a1[0]), s2 = sigf(a2[0]);
    float* sc = out;
    float* si = out + (size_t)20480000;
    float* sp = out + (size_t)40960000;
    for (int nt = 0; nt < 4; nt++) {
        int col = n0 + nt * 16 + (l & 15);
        const u16* bi = ivbf + (size_t)col * 128 + ko;
        const u16* bp = pvbf + (size_t)col * 128 + ko;
        short8 Bi[4], Bp[4];
#pragma unroll
        for (int kb = 0; kb < 4; kb++) {
            Bi[kb] = *(const short8*)(bi + kb * 32);
            Bp[kb] = *(const short8*)(bp + kb * 32);
        }
#pragma unroll
        for (int mi = 0; mi < 4; mi++) {
            f32x4 ai = {0.f, 0.f, 0.f, 0.f}, ap = {0.f, 0.f, 0.f, 0.f};
#pragma unroll
            for (int kb = 0; kb < 4; kb++) {
                ai = mfma16(Ai[mi][kb], Bi[kb], ai);
                ap = mfma16(Ap[mi][kb], Bp[kb], ap);
            }
            int rowb = w * 64 + mi * 16 + (l >> 4) * 4;
#pragma unroll
            for (int q = 0; q < 4; q++) {
                size_t o = (size_t)(rowb + q) * 80000 + col;
                float vi = ai[q], vp = ap[q];
                si[o] = vi;
                sp[o] = vp;
                sc[o] = s1 * vi + s2 * vp;
            }
        }
    }
}

extern "C" void kernel_launch(void* const* d_in, const int* in_sizes, int n_in,
                              void* d_out, int out_size, void* d_ws, size_t ws_size,
                              hipStream_t stream) {
    (void)in_sizes; (void)n_in; (void)out_size; (void)ws_size;
    const int*   sess    = (const int*)d_in[0];
    const int*   lengths = (const int*)d_in[1];
    const float* tau     = (const float*)d_in[4];
    const int*   adj     = (const int*)d_in[5];
    const int*   anchors = (const int*)d_in[6];
    const float* emb     = (const float*)d_in[7];
    const float* W_ih    = (const float*)d_in[8];
    const float* W_hh    = (const float*)d_in[9];
    const float* b_ih    = (const float*)d_in[10];
    const float* b_hh    = (const float*)d_in[11];
    const float* W1      = (const float*)d_in[12];
    const float* b1      = (const float*)d_in[13];
    const float* W2      = (const float*)d_in[14];
    const float* b2      = (const float*)d_in[15];
    const float* a1      = (const float*)d_in[16];
    const float* a2      = (const float*)d_in[17];
    const float* ln1g = (const float*)d_in[18];
    const float* ln1b = (const float*)d_in[19];
    const float* ln2g = (const float*)d_in[20];
    const float* ln2b = (const float*)d_in[21];
    const float* ln3g = (const float*)d_in[22];
    const float* ln3b = (const float*)d_in[23];
    const float* ln4g = (const float*)d_in[24];
    const float* ln4b = (const float*)d_in[25];

    float* out = (float*)d_out;
    // d_out doubles as scratch; all scratch dead before k_scores overwrites it.
    float* o_iv  = out;              // xn1, later item_vectors (f32)
    float* o_o1  = out + SLOT;       // hop-1 output
    float* o_o2  = out + 2 * SLOT;   // hop-2 output
    float* o_hgi = out + 3 * SLOT;   // h (MLP), later gi_all

    u16* ws16  = (u16*)d_ws;         // needs ~41.3 MB
    u16* ivbf  = ws16;               // 10.24M
    u16* pvbf  = ws16 + 10240000;    // 10.24M
    u16* wihbf = ws16 + 20480000;    // 49152
    u16* htbf  = ws16 + 20529152;    // 65536
    u16* w1bf  = ws16 + 20594688;    // 16384

    k_cvt<<<192, 256, 0, stream>>>(W_ih, wihbf, 49152);
    k_cvt<<<64, 256, 0, stream>>>(W1, w1bf, 16384);
    k_norm<<<20000, 256, 0, stream>>>(emb + 128, o_iv);
    k_route<<<5000, 256, 0, stream>>>(o_iv, adj, o_o1);
    // hop-2 input is already unit-norm (routing ends with normalize) -> reuse directly
    k_route<<<5000, 256, 0, stream>>>(o_o1, adj, o_o2);
    k_ln1<<<20000, 256, 0, stream>>>(emb + 128, o_o1, o_o2, ln1g, ln1b, o_iv, (u32*)ivbf);
    k_hmf<<<1250, 256, 0, stream>>>(ivbf, w1bf, b1, o_hgi);
    k_pop2<<<5000, 1024, 0, stream>>>(o_hgi, o_iv, W2, b2, tau, anchors, ln2g, ln2b, (u32*)pvbf);
    k_gi<<<400, 256, 0, stream>>>(sess, ivbf, pvbf, wihbf, b_ih, o_hgi);
    k_gru<<<256, 384, 0, stream>>>(o_hgi, W_hh, b_hh, lengths, ln3g, ln3b, ln4g, ln4b, (u32*)htbf);
    k_scores<<<1250, 256, 0, stream>>>(htbf, ivbf, pvbf, a1, a2, out);
}

// Round 3
// 544.003 us; speedup vs baseline: 1.6703x; 1.4634x over previous
//
#include <hip/hip_runtime.h>

typedef unsigned short u16;
typedef unsigned int u32;
typedef __attribute__((ext_vector_type(8))) short short8;
typedef __attribute__((ext_vector_type(4))) float f32x4;

#define N_IT 80000
#define SLOT 10240000

__device__ __forceinline__ float wred(float v) {
#pragma unroll
    for (int s = 32; s; s >>= 1) v += __shfl_xor(v, s);
    return v;
}
__device__ __forceinline__ float sigf(float x) { return 1.f / (1.f + expf(-x)); }
__device__ __forceinline__ u16 f2bf(float f) {          // RNE f32->bf16
    u32 x = __float_as_uint(f);
    u32 r = x + 0x7fffu + ((x >> 16) & 1u);
    return (u16)(r >> 16);
}
__device__ __forceinline__ f32x4 mfma16(short8 a, short8 b, f32x4 c) {
    return __builtin_amdgcn_mfma_f32_16x16x32_bf16(a, b, c, 0, 0, 0);
}
// xor-swizzle within 32-lane half (BitMode): pattern = (xor<<10)|0x1F
#define SWZ(v, pat) __int_as_float(__builtin_amdgcn_ds_swizzle(__float_as_int(v), pat))
__device__ __forceinline__ float red16(float t) {   // sum over 16-lane group
    t += SWZ(t, 0x041F);
    t += SWZ(t, 0x081F);
    t += SWZ(t, 0x101F);
    t += SWZ(t, 0x201F);
    return t;
}
__device__ __forceinline__ float dot4(float4 a, float4 b) {
    return a.x * b.x + a.y * b.y + a.z * b.z + a.w * b.w;
}

// ---------- f32 -> bf16 convert ----------
__global__ __launch_bounds__(256) void k_cvt(const float* __restrict__ x,
                                             u16* __restrict__ o, int n) {
    int i = blockIdx.x * 256 + threadIdx.x;
    if (i < n) o[i] = f2bf(x[i]);
}

// ---------- row L2-normalize (wave per row, lane holds dims 2l,2l+1) ----------
__global__ __launch_bounds__(256) void k_norm(const float* __restrict__ x,
                                              float* __restrict__ xn) {
    int wid = (blockIdx.x * blockDim.x + threadIdx.x) >> 6;
    int l = threadIdx.x & 63;
    size_t base = (size_t)wid * 128;
    float2 v = *(const float2*)(x + base + 2 * l);
    float s = wred(v.x * v.x + v.y * v.y);
    float r = 1.f / sqrtf(s + 1e-12f);
    *(float2*)(xn + base + 2 * l) = make_float2(v.x * r, v.y * r);
}

// ---------- one routing_agg hop: 16 lanes/item, 8 dims/lane, 4 items/wave ----------
// launch_bounds(256,2): VGPR budget 256 -- z[] (96 VGPR) MUST stay in registers.
// (256,3) made the allocator spill z to scratch: 410 MB of scratch writes, 7x slowdown.
__global__ __launch_bounds__(256, 2) void k_route(const float* __restrict__ xn,
                                                  const int* __restrict__ adj,
                                                  float* __restrict__ out) {
    int tid = blockIdx.x * 256 + threadIdx.x;
    int item = tid >> 4;
    int sl = threadIdx.x & 15;
    const float4* xr = (const float4*)(xn + (size_t)item * 128 + sl * 8);
    float4 x0 = xr[0], x1 = xr[1];
    // adjacency row: 48 B, same address across the 16-lane group (L1 broadcast)
    const int4* ar = (const int4*)(adj + (size_t)(item + 1) * 12);
    int4 a0 = ar[0], a1 = ar[1], a2 = ar[2];
    float4 z0[12], z1[12];
#define LDZ(i, comp)                                                            \
    {                                                                           \
        const float4* zr = (const float4*)(xn + (size_t)((comp) - 1) * 128 + sl * 8); \
        z0[i] = zr[0]; z1[i] = zr[1];                                           \
    }
    LDZ(0, a0.x) LDZ(1, a0.y) LDZ(2, a0.z) LDZ(3, a0.w)
    LDZ(4, a1.x) LDZ(5, a1.y) LDZ(6, a1.z) LDZ(7, a1.w)
    LDZ(8, a2.x) LDZ(9, a2.y) LDZ(10, a2.z) LDZ(11, a2.w)
#undef LDZ
    float4 u0 = x0, u1 = x1;
#pragma unroll
    for (int it = 0; it < 4; it++) {
        float p[12]; float sum = 0.f;
#pragma unroll
        for (int m = 0; m < 12; m++) {
            float t = dot4(u0, z0[m]) + dot4(u1, z1[m]);
            t = red16(t);
            // u,z unit vectors -> |t|<=1: softmax max-subtraction unnecessary
            p[m] = __expf(t);
            sum += p[m];
        }
        float inv = 1.f / sum;
        u0 = x0; u1 = x1;
#pragma unroll
        for (int m = 0; m < 12; m++) {
            float pm = p[m] * inv;
            u0.x += pm * z0[m].x; u0.y += pm * z0[m].y;
            u0.z += pm * z0[m].z; u0.w += pm * z0[m].w;
            u1.x += pm * z1[m].x; u1.y += pm * z1[m].y;
            u1.z += pm * z1[m].z; u1.w += pm * z1[m].w;
        }
        float nn = red16(dot4(u0, u0) + dot4(u1, u1));
        float rr = 1.f / sqrtf(nn + 1e-12f);
        u0.x *= rr; u0.y *= rr; u0.z *= rr; u0.w *= rr;
        u1.x *= rr; u1.y *= rr; u1.z *= rr; u1.w *= rr;
    }
    float4* orow = (float4*)(out + (size_t)item * 128 + sl * 8);
    orow[0] = u0; orow[1] = u1;
}

// ---------- item_vectors = LN(emb[1:] + out1 + out2); also bf16 copy ----------
__global__ __launch_bounds__(256) void k_ln1(const float* __restrict__ x,
                                             const float* __restrict__ o1,
                                             const float* __restrict__ o2,
                                             const float* __restrict__ g,
                                             const float* __restrict__ bb,
                                             float* __restrict__ iv,
                                             u32* __restrict__ ivbf) {
    int wid = (blockIdx.x * blockDim.x + threadIdx.x) >> 6;
    int l = threadIdx.x & 63;
    size_t base = (size_t)wid * 128;
    float2 xa = *(const float2*)(x + base + 2 * l);
    float2 xb = *(const float2*)(o1 + base + 2 * l);
    float2 xc = *(const float2*)(o2 + base + 2 * l);
    float v0 = xa.x + xb.x + xc.x;
    float v1 = xa.y + xb.y + xc.y;
    float s = wred(v0 + v1);
    float q = wred(v0 * v0 + v1 * v1);
    float mean = s * (1.f / 128.f);
    float var = q * (1.f / 128.f) - mean * mean;
    float r = 1.f / sqrtf(var + 1e-5f);
    float2 gg = *(const float2*)(g + 2 * l);
    float2 bg = *(const float2*)(bb + 2 * l);
    float y0 = (v0 - mean) * r * gg.x + bg.x;
    float y1 = (v1 - mean) * r * gg.y + bg.y;
    *(float2*)(iv + base + 2 * l) = make_float2(y0, y1);
    ivbf[(size_t)wid * 64 + l] = ((u32)f2bf(y1) << 16) | f2bf(y0);
}

// ---------- h = leaky_relu(iv @ W1^T + b1) via bf16 MFMA ----------
__global__ __launch_bounds__(256) void k_hmf(const u16* __restrict__ ivbf,
                                             const u16* __restrict__ w1bf,
                                             const float* __restrict__ b1,
                                             float* __restrict__ h) {
    int w = threadIdx.x >> 6, l = threadIdx.x & 63;
    int mt = blockIdx.x * 4 + w;
    int row = mt * 16 + (l & 15);
    int ko = (l >> 4) * 8;
    const u16* ap = ivbf + (size_t)row * 128 + ko;
    short8 A[4];
#pragma unroll
    for (int kb = 0; kb < 4; kb++) A[kb] = *(const short8*)(ap + kb * 32);
    int rowb = mt * 16 + (l >> 4) * 4;
    for (int nt = 0; nt < 8; nt++) {
        int col = nt * 16 + (l & 15);
        const u16* wp = w1bf + col * 128 + ko;
        f32x4 acc = {0.f, 0.f, 0.f, 0.f};
#pragma unroll
        for (int kb = 0; kb < 4; kb++)
            acc = mfma16(A[kb], *(const short8*)(wp + kb * 32), acc);
        float bias = b1[col];
#pragma unroll
        for (int q = 0; q < 4; q++) {
            float v = acc[q] + bias;
            h[(size_t)(rowb + q) * 128 + col] = v >= 0.f ? v : 0.01f * v;
        }
    }
}

// ---------- pop logits -> softmax -> @anchors_emb -> LN2 -> pv (bf16) ----------
__global__ __launch_bounds__(1024) void k_pop2(const float* __restrict__ h,
                                               const float* __restrict__ iv,
                                               const float* __restrict__ W2,
                                               const float* __restrict__ b2,
                                               const float* __restrict__ tau,
                                               const int* __restrict__ anchors,
                                               const float* __restrict__ g2,
                                               const float* __restrict__ bb2,
                                               u32* __restrict__ pvbf) {
    __shared__ float W2T[128][20];
    __shared__ __align__(8) float anch[20][128];
    __shared__ __align__(8) float hst[16][128];
    __shared__ float lst[16][20];
    int tid = threadIdx.x;
    for (int e = tid; e < 20 * 128; e += 1024) {
        int k = e >> 7, d = e & 127;
        W2T[d][k] = W2[e];
        anch[k][d] = iv[(size_t)(anchors[k] - 1) * 128 + d];
    }
    __syncthreads();
    int w = tid >> 6, l = tid & 63;
    int item = blockIdx.x * 16 + w;
    const float* hr = h + (size_t)item * 128;
    float2 hv = *(const float2*)(hr + 2 * l);
    *(float2*)&hst[w][2 * l] = hv;
    if (l < 20) {
        float acc = b2[l];
        for (int j = 0; j < 128; j++) acc += hst[w][j] * W2T[j][l];
        lst[w][l] = acc / tau[0];
    }
    float p[20]; float mx = -1e30f;
#pragma unroll
    for (int k = 0; k < 20; k++) { p[k] = lst[w][k]; mx = fmaxf(mx, p[k]); }
    float sum = 0.f;
#pragma unroll
    for (int k = 0; k < 20; k++) { p[k] = expf(p[k] - mx); sum += p[k]; }
    float inv = 1.f / sum;
    float o0 = 0.f, o1 = 0.f;
#pragma unroll
    for (int k = 0; k < 20; k++) {
        float pk = p[k] * inv;
        float2 av = *(const float2*)&anch[k][2 * l];
        o0 += pk * av.x; o1 += pk * av.y;
    }
    float s = wred(o0 + o1), q = wred(o0 * o0 + o1 * o1);
    float mean = s * (1.f / 128.f);
    float var = q * (1.f / 128.f) - mean * mean;
    float rr = 1.f / sqrtf(var + 1e-5f);
    float2 gg = *(const float2*)(g2 + 2 * l);
    float2 bg = *(const float2*)(bb2 + 2 * l);
    float y0 = (o0 - mean) * rr * gg.x + bg.x;
    float y1 = (o1 - mean) * rr * gg.y + bg.y;
    pvbf[(size_t)item * 64 + l] = ((u32)f2bf(y1) << 16) | f2bf(y0);
}

// ---------- gi_all[512*50][384] = gather(iv/pv)[sess] @ W_ih^T + b_ih ----------
__global__ __launch_bounds__(256) void k_gi(const int* __restrict__ sess,
                                            const u16* __restrict__ ivbf,
                                            const u16* __restrict__ pvbf,
                                            const u16* __restrict__ wbf,
                                            const float* __restrict__ bih,
                                            float* __restrict__ gi) {
    int w = threadIdx.x >> 6, l = threadIdx.x & 63;
    int mt = blockIdx.x * 4 + w;
    int r = mt * 16 + (l & 15);
    int s = r / 50, t = r - s * 50;
    int idx = sess[(s & 255) * 50 + t];
    const u16* srcb = (s < 256) ? ivbf : pvbf;
    int ko = (l >> 4) * 8;
    const short8 Z8 = {0, 0, 0, 0, 0, 0, 0, 0};
    short8 A[4];
    if (idx == 0) {
#pragma unroll
        for (int kb = 0; kb < 4; kb++) A[kb] = Z8;
    } else {
        const u16* rp = srcb + (size_t)(idx - 1) * 128 + ko;
#pragma unroll
        for (int kb = 0; kb < 4; kb++) A[kb] = *(const short8*)(rp + kb * 32);
    }
    int rowb = mt * 16 + (l >> 4) * 4;
    for (int nt = 0; nt < 24; nt++) {
        int gcol = nt * 16 + (l & 15);
        const u16* wp = wbf + gcol * 128 + ko;
        f32x4 acc = {0.f, 0.f, 0.f, 0.f};
#pragma unroll
        for (int kb = 0; kb < 4; kb++)
            acc = mfma16(A[kb], *(const short8*)(wp + kb * 32), acc);
        float bias = bih[gcol];
#pragma unroll
        for (int q = 0; q < 4; q++)
            gi[(size_t)(rowb + q) * 384 + gcol] = acc[q] + bias;
    }
}

// ---------- dual GRU: block b runs seq b (item) and b+256 (pop); W_hh rows in VGPRs ----------
__global__ __launch_bounds__(384, 2) void k_gru(const float* __restrict__ gi,
                                                const float* __restrict__ whh,
                                                const float* __restrict__ bhh,
                                                const int* __restrict__ lengths,
                                                const float* __restrict__ g3,
                                                const float* __restrict__ b3,
                                                const float* __restrict__ g4,
                                                const float* __restrict__ b4,
                                                u32* __restrict__ htbf) {
    __shared__ __align__(16) float hA[2][128], hB[2][128];
    __shared__ float rA[128], zA[128], hnA[128], inA[128];
    __shared__ float rB[128], zB[128], hnB[128], inB[128];
    int g = threadIdx.x, b = blockIdx.x;
    float4 wv[32];
    const float4* wr = (const float4*)(whh + g * 128);
#pragma unroll
    for (int k = 0; k < 32; k++) wv[k] = wr[k];
    float bh = bhh[g];
    if (g < 128) { hA[0][g] = 0.f; hB[0][g] = 0.f; }
    int len = lengths[b];
    const float* giA = gi + (size_t)b * 50 * 384 + g;
    const float* giB = gi + (size_t)(b + 256) * 50 * 384 + g;
    __syncthreads();
    int par = 0;
    for (int t = 0; t < len; t++) {
        float ga = giA[t * 384], gb = giB[t * 384];
        float aA = bh, aB = bh;
#pragma unroll
        for (int k = 0; k < 32; k++) {
            float4 w4 = wv[k];
            float4 ha = *(const float4*)&hA[par][k * 4];
            float4 hb = *(const float4*)&hB[par][k * 4];
            aA += w4.x * ha.x + w4.y * ha.y + w4.z * ha.z + w4.w * ha.w;
            aB += w4.x * hb.x + w4.y * hb.y + w4.z * hb.z + w4.w * hb.w;
        }
        if (g < 128) {
            rA[g] = sigf(ga + aA); rB[g] = sigf(gb + aB);
        } else if (g < 256) {
            zA[g - 128] = sigf(ga + aA); zB[g - 128] = sigf(gb + aB);
        } else {
            inA[g - 256] = ga; hnA[g - 256] = aA;
            inB[g - 256] = gb; hnB[g - 256] = aB;
        }
        __syncthreads();
        if (g < 128) {
            float n = tanhf(inA[g] + rA[g] * hnA[g]);
            hA[par ^ 1][g] = (1.f - zA[g]) * n + zA[g] * hA[par][g];
        } else if (g < 256) {
            int d = g - 128;
            float n = tanhf(inB[d] + rB[d] * hnB[d]);
            hB[par ^ 1][d] = (1.f - zB[d]) * n + zB[d] * hB[par][d];
        }
        __syncthreads();
        par ^= 1;
    }
    int w = g >> 6, l = g & 63;
    if (w == 0) {
        float2 v = *(const float2*)&hA[par][2 * l];
        float s = wred(v.x + v.y), q = wred(v.x * v.x + v.y * v.y);
        float mean = s * (1.f / 128.f), var = q * (1.f / 128.f) - mean * mean;
        float r = 1.f / sqrtf(var + 1e-5f);
        float2 gg = *(const float2*)(g3 + 2 * l), bg = *(const float2*)(b3 + 2 * l);
        float y0 = (v.x - mean) * r * gg.x + bg.x;
        float y1 = (v.y - mean) * r * gg.y + bg.y;
        htbf[(size_t)b * 64 + l] = ((u32)f2bf(y1) << 16) | f2bf(y0);
    } else if (w == 1) {
        float2 v = *(const float2*)&hB[par][2 * l];
        float s = wred(v.x + v.y), q = wred(v.x * v.x + v.y * v.y);
        float mean = s * (1.f / 128.f), var = q * (1.f / 128.f) - mean * mean;
        float r = 1.f / sqrtf(var + 1e-5f);
        float2 gg = *(const float2*)(g4 + 2 * l), bg = *(const float2*)(b4 + 2 * l);
        float y0 = (v.x - mean) * r * gg.x + bg.x;
        float y1 = (v.y - mean) * r * gg.y + bg.y;
        htbf[(size_t)(b + 256) * 64 + l] = ((u32)f2bf(y1) << 16) | f2bf(y0);
    }
}

// ---------- scores: BM=256(all) x BN=64/block, bf16 MFMA, 3 outputs ----------
__global__ __launch_bounds__(256) void k_scores(const u16* __restrict__ htbf,
                                                const u16* __restrict__ ivbf,
                                                const u16* __restrict__ pvbf,
                                                const float* __restrict__ a1,
                                                const float* __restrict__ a2,
                                                float* __restrict__ out) {
    int w = threadIdx.x >> 6, l = threadIdx.x & 63;
    int n0 = blockIdx.x * 64;
    int ko = (l >> 4) * 8;
    short8 Ai[4][4], Ap[4][4];
#pragma unroll
    for (int mi = 0; mi < 4; mi++) {
        int row = w * 64 + mi * 16 + (l & 15);
        const u16* pi = htbf + row * 128 + ko;
        const u16* pp = htbf + (row + 256) * 128 + ko;
#pragma unroll
        for (int kb = 0; kb < 4; kb++) {
            Ai[mi][kb] = *(const short8*)(pi + kb * 32);
            Ap[mi][kb] = *(const short8*)(pp + kb * 32);
        }
    }
    float s1 = sigf(a1[0]), s2 = sigf(a2[0]);
    float* sc = out;
    float* si = out + (size_t)20480000;
    float* sp = out + (size_t)40960000;
    for (int nt = 0; nt < 4; nt++) {
        int col = n0 + nt * 16 + (l & 15);
        const u16* bi = ivbf + (size_t)col * 128 + ko;
        const u16* bp = pvbf + (size_t)col * 128 + ko;
        short8 Bi[4], Bp[4];
#pragma unroll
        for (int kb = 0; kb < 4; kb++) {
            Bi[kb] = *(const short8*)(bi + kb * 32);
            Bp[kb] = *(const short8*)(bp + kb * 32);
        }
#pragma unroll
        for (int mi = 0; mi < 4; mi++) {
            f32x4 ai = {0.f, 0.f, 0.f, 0.f}, ap = {0.f, 0.f, 0.f, 0.f};
#pragma unroll
            for (int kb = 0; kb < 4; kb++) {
                ai = mfma16(Ai[mi][kb], Bi[kb], ai);
                ap = mfma16(Ap[mi][kb], Bp[kb], ap);
            }
            int rowb = w * 64 + mi * 16 + (l >> 4) * 4;
#pragma unroll
            for (int q = 0; q < 4; q++) {
                size_t o = (size_t)(rowb + q) * 80000 + col;
                float vi = ai[q], vp = ap[q];
                si[o] = vi;
                sp[o] = vp;
                sc[o] = s1 * vi + s2 * vp;
            }
        }
    }
}

extern "C" void kernel_launch(void* const* d_in, const int* in_sizes, int n_in,
                              void* d_out, int out_size, void* d_ws, size_t ws_size,
                              hipStream_t stream) {
    (void)in_sizes; (void)n_in; (void)out_size; (void)ws_size;
    const int*   sess    = (const int*)d_in[0];
    const int*   lengths = (const int*)d_in[1];
    const float* tau     = (const float*)d_in[4];
    const int*   adj     = (const int*)d_in[5];
    const int*   anchors = (const int*)d_in[6];
    const float* emb     = (const float*)d_in[7];
    const float* W_ih    = (const float*)d_in[8];
    const float* W_hh    = (const float*)d_in[9];
    const float* b_ih    = (const float*)d_in[10];
    const float* b_hh    = (const float*)d_in[11];
    const float* W1      = (const float*)d_in[12];
    const float* b1      = (const float*)d_in[13];
    const float* W2      = (const float*)d_in[14];
    const float* b2      = (const float*)d_in[15];
    const float* a1      = (const float*)d_in[16];
    const float* a2      = (const float*)d_in[17];
    const float* ln1g = (const float*)d_in[18];
    const float* ln1b = (const float*)d_in[19];
    const float* ln2g = (const float*)d_in[20];
    const float* ln2b = (const float*)d_in[21];
    const float* ln3g = (const float*)d_in[22];
    const float* ln3b = (const float*)d_in[23];
    const float* ln4g = (const float*)d_in[24];
    const float* ln4b = (const float*)d_in[25];

    float* out = (float*)d_out;
    // d_out doubles as scratch; all scratch dead before k_scores overwrites it.
    float* o_iv  = out;              // xn1, later item_vectors (f32)
    float* o_o1  = out + SLOT;       // hop-1 output
    float* o_o2  = out + 2 * SLOT;   // hop-2 output
    float* o_hgi = out + 3 * SLOT;   // h (MLP), later gi_all

    u16* ws16  = (u16*)d_ws;         // needs ~41.3 MB
    u16* ivbf  = ws16;               // 10.24M
    u16* pvbf  = ws16 + 10240000;    // 10.24M
    u16* wihbf = ws16 + 20480000;    // 49152
    u16* htbf  = ws16 + 20529152;    // 65536
    u16* w1bf  = ws16 + 20594688;    // 16384

    k_cvt<<<192, 256, 0, stream>>>(W_ih, wihbf, 49152);
    k_cvt<<<64, 256, 0, stream>>>(W1, w1bf, 16384);
    k_norm<<<20000, 256, 0, stream>>>(emb + 128, o_iv);
    k_route<<<5000, 256, 0, stream>>>(o_iv, adj, o_o1);
    // hop-2 input is already unit-norm (routing ends with normalize) -> reuse directly
    k_route<<<5000, 256, 0, stream>>>(o_o1, adj, o_o2);
    k_ln1<<<20000, 256, 0, stream>>>(emb + 128, o_o1, o_o2, ln1g, ln1b, o_iv, (u32*)ivbf);
    k_hmf<<<1250, 256, 0, stream>>>(ivbf, w1bf, b1, o_hgi);
    k_pop2<<<5000, 1024, 0, stream>>>(o_hgi, o_iv, W2, b2, tau, anchors, ln2g, ln2b, (u32*)pvbf);
    k_gi<<<400, 256, 0, stream>>>(sess, ivbf, pvbf, wihbf, b_ih, o_hgi);
    k_gru<<<256, 384, 0, stream>>>(o_hgi, W_hh, b_hh, lengths, ln3g, ln3b, ln4g, ln4b, (u32*)htbf);
    k_scores<<<1250, 256, 0, stream>>>(htbf, ivbf, pvbf, a1, a2, out);
}